// Round 1
// baseline (251.226 us; speedup 1.0000x reference)
//
#include <hip/hip_runtime.h>

#define D      128
#define DH     32
#define NH     4
#define DM     64
#define DMLP   512
#define PMAX   150
#define VOC    152
#define EQT    151
#define NBATCH 65536

typedef __attribute__((ext_vector_type(8))) __bf16 bf16x8;
typedef __attribute__((ext_vector_type(4))) float  f32x4;

__device__ __forceinline__ float silu_f(float x){ return x / (1.0f + expf(-x)); }

// ---- workspace layout (float offsets) ----
#define OFF_MEMVEC 0        // 150*128
#define OFF_X3BASE 19200    // 128
#define OFF_Q3     19328    // 150*128
#define OFF_KE     38528    // 152*128
#define OFF_KM     57984    // 150*128
#define OFF_KP     77184    // 4*128
#define OFF_EV     77696    // 152*128
#define OFF_MV     97152    // 150*128
#define OFF_PV     116352   // 4*128
#define OFF_OVE    116864   // 152*512  [v][h*128+m]
#define OFF_OVP    194688   // 4*512    [t][h*128+m]
#define OFF_M3     196736   // 150*128
#define OFF_W1F    215936   // 65536 bf16 (as floats: 32768)
#define OFF_W2F    248704   // 65536 bf16
#define OFF_WUF    281472   // 20480 bf16

// ================= K1: memvec[p] (150 blocks) + x3base (1 block) ============
__global__ void k_prep1(const float* __restrict__ tok, const float* __restrict__ pos,
                        const float* __restrict__ W_mem, const float* __restrict__ b_mem,
                        const float* __restrict__ W_sur, const float* __restrict__ b_sur,
                        const float* __restrict__ W_m2r, const float* __restrict__ b_m2r,
                        float* __restrict__ memvec, float* __restrict__ x3base)
{
    int t = threadIdx.x;
    if (blockIdx.x == PMAX) {
        x3base[t] = tok[EQT*D + t] + pos[3*D + t];
        return;
    }
    int p = blockIdx.x;
    __shared__ float sx0[D], sz[DM], sdiff[D], szu[DM];
    sx0[t] = tok[p*D + t] + pos[t];
    __syncthreads();
    if (t < DM) {
        float acc = b_mem[t];
        for (int d = 0; d < D; d++) acc += sx0[d] * W_mem[d*DM + t];
        sz[t] = silu_f(acc);
    }
    __syncthreads();
    {
        float acc = b_sur[t];
        for (int j = 0; j < DM; j++) acc += sz[j] * W_sur[j*D + t];
        sdiff[t] = sx0[t] - acc;
    }
    __syncthreads();
    if (t < DM) {
        float acc = 0.f;
        for (int d = 0; d < D; d++) acc += sdiff[d] * W_mem[d*DM + t];
        szu[t] = sz[t] + silu_f(acc);
    }
    __syncthreads();
    {
        float acc = b_m2r[t];
        for (int j = 0; j < DM; j++) acc += szu[j] * W_m2r[j*D + t];
        memvec[p*D + t] = acc;
    }
}

// ================= K2: QKV-style projections (762 blocks x 128) =============
// W_{Q,K,V} layout (H,128,32): concat col c -> h=c>>5, k=c&31
__global__ void k_prep2(const float* __restrict__ tok, const float* __restrict__ pos,
                        const float* __restrict__ memvec, const float* __restrict__ x3base,
                        const float* __restrict__ W_Q, const float* __restrict__ W_K,
                        const float* __restrict__ W_V,
                        float* __restrict__ KE, float* __restrict__ KM, float* __restrict__ KP,
                        float* __restrict__ Q3, float* __restrict__ EV, float* __restrict__ MV,
                        float* __restrict__ PV)
{
    int r = blockIdx.x, t = threadIdx.x;
    const float* src; const float* add = nullptr; const float* W; float* out;
    if      (r < 152) { src = tok    + r*D;          W = W_K; out = KE + r*D; }
    else if (r < 302) { src = memvec + (r-152)*D;    W = W_K; out = KM + (r-152)*D; }
    else if (r < 306) { src = pos    + (r-302)*D;    W = W_K; out = KP + (r-302)*D; }
    else if (r < 456) { src = memvec + (r-306)*D; add = x3base; W = W_Q; out = Q3 + (r-306)*D; }
    else if (r < 608) { src = tok    + (r-456)*D;    W = W_V; out = EV + (r-456)*D; }
    else if (r < 758) { src = memvec + (r-608)*D;    W = W_V; out = MV + (r-608)*D; }
    else              { src = pos    + (r-758)*D;    W = W_V; out = PV + (r-758)*D; }
    __shared__ float s[D];
    s[t] = src[t] + (add ? add[t] : 0.f);
    __syncthreads();
    int h = t >> 5, k = t & 31;
    float acc = 0.f;
    for (int d = 0; d < D; d++) acc += s[d] * W[h*4096 + d*32 + k];
    out[t] = acc;
}

// ===== K3: OV tables + M3 + bf16 fragment repack (380 blocks x 256) =========
__global__ void k_prep3(const float* __restrict__ EV, const float* __restrict__ MV,
                        const float* __restrict__ PV, const float* __restrict__ memvec,
                        const float* __restrict__ W_O,
                        const float* __restrict__ W1, const float* __restrict__ W2,
                        const float* __restrict__ WU,
                        float* __restrict__ OVE, float* __restrict__ OVP, float* __restrict__ M3,
                        __bf16* __restrict__ W1f, __bf16* __restrict__ W2f, __bf16* __restrict__ WUf)
{
    int r = blockIdx.x, t = threadIdx.x;
    if (r < 156) {
        // OVE rows (v<152) and OVP rows (t=0..3): out[c], c = h*128+m
        const float* src = (r < 152) ? (EV + r*D)   : (PV + (r-152)*D);
        float*       out = (r < 152) ? (OVE + r*512) : (OVP + (r-152)*512);
        __shared__ float s[D];
        if (t < D) s[t] = src[t];
        __syncthreads();
        #pragma unroll
        for (int i = 0; i < 2; i++) {
            int c = t + i*256;
            int h = c >> 7, m = c & 127;
            float acc = 0.f;
            for (int k = 0; k < 32; k++) acc += s[h*32 + k] * W_O[h*4096 + k*128 + m];
            out[c] = acc;
        }
    } else if (r < 306) {
        // M3[p] = memvec[p] + MV[p] @ W_O_flat  (sum over all heads)
        int p = r - 156;
        __shared__ float s2[D];
        if (t < D) s2[t] = MV[p*D + t];
        __syncthreads();
        if (t < D) {
            float acc = memvec[p*D + t];
            for (int c = 0; c < D; c++) acc += s2[c] * W_O[c*128 + t];
            M3[p*D + t] = acc;
        }
    } else if (r < 338) {
        // W1 (128x512): frag f = (nb*4+kb)*64+l
        int f = (r-306)*256 + t;
        int l = f & 63, kb = (f>>6) & 3, nb = f >> 8;
        int k0 = kb*32 + (l>>4)*8, n = nb*16 + (l&15);
        #pragma unroll
        for (int j = 0; j < 8; j++) W1f[f*8 + j] = (__bf16)W1[(k0+j)*DMLP + n];
    } else if (r < 370) {
        // W2 (512x128): frag f = (nb*16+kb)*64+l
        int f = (r-338)*256 + t;
        int l = f & 63, kb = (f>>6) & 15, nb = f >> 10;
        int k0 = kb*32 + (l>>4)*8, n = nb*16 + (l&15);
        #pragma unroll
        for (int j = 0; j < 8; j++) W2f[f*8 + j] = (__bf16)W2[(k0+j)*D + n];
    } else {
        // W_un (128x150 -> padded N=160): frag f = (nt*4+kb)*64+l
        int f = (r-370)*256 + t;
        int l = f & 63, kb = (f>>6) & 3, nb = f >> 8;
        int k0 = kb*32 + (l>>4)*8, n = nb*16 + (l&15);
        #pragma unroll
        for (int j = 0; j < 8; j++) WUf[f*8 + j] = (__bf16)((n < 150) ? WU[(k0+j)*150 + n] : 0.f);
    }
}

// ===================== K4: main fused kernel (1024 blocks x 256) ============
__global__ __launch_bounds__(256, 2) void k_main(
    const int* __restrict__ p_val, const int* __restrict__ a_tok, const int* __restrict__ b_tok,
    const float* __restrict__ Q3, const float* __restrict__ KE, const float* __restrict__ KM,
    const float* __restrict__ KPg, const float* __restrict__ OVE, const float* __restrict__ OVPg,
    const float* __restrict__ M3, const float* __restrict__ x3baseg,
    const __bf16* __restrict__ W1f, const __bf16* __restrict__ W2f, const __bf16* __restrict__ WUf,
    const float* __restrict__ b1, const float* __restrict__ b2, const float* __restrict__ bun,
    float* __restrict__ out)
{
    __shared__ __align__(16) __bf16 sX3[64*136];   // x3 bf16, A-frag layout, +8 pad
    __shared__ __align__(16) __bf16 sH [64*264];   // H chunk (256 cols) +8 pad
    __shared__ __align__(16) float  sW  [64*16];
    __shared__ __align__(16) float  sKP [4*128];
    __shared__ __align__(16) float  sOVP[4*512];
    __shared__ __align__(16) float  sOVEq[512];
    __shared__ __align__(16) float  sBase[128];

    int tid = threadIdx.x;
    int gbase = blockIdx.x * 64;

    for (int i = tid; i < 2048; i += 256) sOVP[i] = OVPg[i];
    for (int i = tid; i < 512;  i += 256) { sKP[i] = KPg[i]; sOVEq[i] = OVE[EQT*512 + i]; }
    if (tid < 128) sBase[tid] = x3baseg[tid];
    __syncthreads();

    // ---------- phase 1a: scores + softmax (thread = (sample, head)) --------
    {
        int s = tid >> 2, h = tid & 3;
        int gs = gbase + s;
        int p = p_val[gs], ta = a_tok[gs], tb = b_tok[gs];
        int ho4 = h * 8;
        const float4* qv  = (const float4*)(Q3 + p*D)   + ho4;
        const float4* km  = (const float4*)(KM + p*D)   + ho4;
        const float4* pe0 = (const float4*)(KE + p*D)   + ho4;
        const float4* pe1 = (const float4*)(KE + ta*D)  + ho4;
        const float4* pe2 = (const float4*)(KE + tb*D)  + ho4;
        const float4* pe3 = (const float4*)(KE + EQT*D) + ho4;
        const float4* kp  = (const float4*)sKP;
        float s0 = 0.f, s1 = 0.f, s2 = 0.f, s3 = 0.f;
        #pragma unroll
        for (int kk = 0; kk < 8; kk++) {
            float4 q = qv[kk], m = km[kk];
            float4 p0 = kp[0*32 + ho4 + kk], p1 = kp[1*32 + ho4 + kk];
            float4 p2 = kp[2*32 + ho4 + kk], p3 = kp[3*32 + ho4 + kk];
            float4 e0 = pe0[kk], e1 = pe1[kk], e2 = pe2[kk], e3 = pe3[kk];
            s0 += q.x*(e0.x+p0.x+m.x) + q.y*(e0.y+p0.y+m.y) + q.z*(e0.z+p0.z+m.z) + q.w*(e0.w+p0.w+m.w);
            s1 += q.x*(e1.x+p1.x+m.x) + q.y*(e1.y+p1.y+m.y) + q.z*(e1.z+p1.z+m.z) + q.w*(e1.w+p1.w+m.w);
            s2 += q.x*(e2.x+p2.x+m.x) + q.y*(e2.y+p2.y+m.y) + q.z*(e2.z+p2.z+m.z) + q.w*(e2.w+p2.w+m.w);
            s3 += q.x*(e3.x+p3.x+m.x) + q.y*(e3.y+p3.y+m.y) + q.z*(e3.z+p3.z+m.z) + q.w*(e3.w+p3.w+m.w);
        }
        const float scale = 0.17677669529663687f;  // 1/sqrt(32)
        s0 *= scale; s1 *= scale; s2 *= scale; s3 *= scale;
        float mx = fmaxf(fmaxf(s0, s1), fmaxf(s2, s3));
        float e0 = expf(s0-mx), e1 = expf(s1-mx), e2 = expf(s2-mx), e3 = expf(s3-mx);
        float inv = 1.f / (e0 + e1 + e2 + e3);
        sW[s*16 + h*4 + 0] = e0*inv; sW[s*16 + h*4 + 1] = e1*inv;
        sW[s*16 + h*4 + 2] = e2*inv; sW[s*16 + h*4 + 3] = e3*inv;
    }
    __syncthreads();

    // ---------- phase 1b: x3 = base + M3[p] + weighted OV tables ------------
    {
        int s = tid >> 2, q = tid & 3;
        int gs = gbase + s;
        int p = p_val[gs], ta = a_tok[gs], tb = b_tok[gs];
        float w[16];
        #pragma unroll
        for (int i = 0; i < 16; i++) w[i] = sW[s*16 + i];
        const float4* m3    = (const float4*)(M3 + p*D);
        const float4* base4 = (const float4*)sBase;
        const float4* ovp4  = (const float4*)sOVP;
        const float4* oveq4 = (const float4*)sOVEq;
        const float4* ove_p = (const float4*)(OVE + p*512);
        const float4* ove_a = (const float4*)(OVE + ta*512);
        const float4* ove_b = (const float4*)(OVE + tb*512);
        #pragma unroll
        for (int j4 = 0; j4 < 8; j4++) {
            int c4 = q*8 + j4;
            float4 v = base4[c4];
            float4 g = m3[c4];
            v.x += g.x; v.y += g.y; v.z += g.z; v.w += g.w;
            #pragma unroll
            for (int h = 0; h < NH; h++) {
                int o4 = h*32 + c4;
                float4 ep = ove_p[o4], ea = ove_a[o4], eb = ove_b[o4], eq = oveq4[o4];
                float4 q0 = ovp4[0*128+o4], q1 = ovp4[1*128+o4], q2 = ovp4[2*128+o4], q3v = ovp4[3*128+o4];
                float w0 = w[h*4+0], w1 = w[h*4+1], w2 = w[h*4+2], w3 = w[h*4+3];
                v.x += w0*(ep.x+q0.x) + w1*(ea.x+q1.x) + w2*(eb.x+q2.x) + w3*(eq.x+q3v.x);
                v.y += w0*(ep.y+q0.y) + w1*(ea.y+q1.y) + w2*(eb.y+q2.y) + w3*(eq.y+q3v.y);
                v.z += w0*(ep.z+q0.z) + w1*(ea.z+q1.z) + w2*(eb.z+q2.z) + w3*(eq.z+q3v.z);
                v.w += w0*(ep.w+q0.w) + w1*(ea.w+q1.w) + w2*(eb.w+q2.w) + w3*(eq.w+q3v.w);
            }
            int c = q*32 + j4*4;
            sX3[s*136 + c + 0] = (__bf16)v.x;
            sX3[s*136 + c + 1] = (__bf16)v.y;
            sX3[s*136 + c + 2] = (__bf16)v.z;
            sX3[s*136 + c + 3] = (__bf16)v.w;
        }
    }
    __syncthreads();

    // ---------- phase 2: MFMA MLP + unembed (wave = 16-row stripe) ----------
    {
        int wv = tid >> 6, l = tid & 63;
        int lr = l & 15, quad = l >> 4;
        int mrow = wv * 16;
        const bf16x8* W1v = (const bf16x8*)W1f;
        const bf16x8* W2v = (const bf16x8*)W2f;
        const bf16x8* WUv = (const bf16x8*)WUf;

        bf16x8 a[4];
        #pragma unroll
        for (int kb = 0; kb < 4; kb++)
            a[kb] = *(const bf16x8*)(sX3 + (mrow + lr)*136 + kb*32 + quad*8);

        f32x4 acc2[8];
        #pragma unroll
        for (int i = 0; i < 8; i++) acc2[i] = (f32x4){0.f, 0.f, 0.f, 0.f};

        for (int cc = 0; cc < 2; cc++) {
            // MLP1 chunk: cols [cc*256, cc*256+256)
            #pragma unroll
            for (int nb = 0; nb < 16; nb++) {
                int nbg = cc*16 + nb;
                int n = nbg*16 + lr;
                float bv = b1[n];
                f32x4 acc = (f32x4){bv, bv, bv, bv};
                #pragma unroll
                for (int kb = 0; kb < 4; kb++)
                    acc = __builtin_amdgcn_mfma_f32_16x16x32_bf16(a[kb], W1v[(nbg*4 + kb)*64 + l], acc, 0, 0, 0);
                int colbase = nb*16 + lr;
                #pragma unroll
                for (int r = 0; r < 4; r++) {
                    float hv = fmaxf(acc[r], 0.f);
                    sH[(mrow + quad*4 + r)*264 + colbase] = (__bf16)hv;
                }
            }
            __syncthreads();
            // MLP2 partial over this chunk's K range
            #pragma unroll
            for (int kb2 = 0; kb2 < 8; kb2++) {
                bf16x8 a2 = *(const bf16x8*)(sH + (mrow + lr)*264 + kb2*32 + quad*8);
                int kbg = cc*8 + kb2;
                #pragma unroll
                for (int nb2 = 0; nb2 < 8; nb2++)
                    acc2[nb2] = __builtin_amdgcn_mfma_f32_16x16x32_bf16(a2, W2v[(nb2*16 + kbg)*64 + l], acc2[nb2], 0, 0, 0);
            }
            __syncthreads();
        }

        // finalize x3'' = x3 + mlp_out + b2  (write back into sX3)
        #pragma unroll
        for (int nb2 = 0; nb2 < 8; nb2++) {
            int n = nb2*16 + lr;
            #pragma unroll
            for (int r = 0; r < 4; r++) {
                int row = mrow + quad*4 + r;
                float v = acc2[nb2][r] + b2[n] + (float)sX3[row*136 + n];
                sX3[row*136 + n] = (__bf16)v;
            }
        }
        __syncthreads();

        // unembed: x3'' @ WU (+ b_un), N padded to 160
        bf16x8 au[4];
        #pragma unroll
        for (int kb = 0; kb < 4; kb++)
            au[kb] = *(const bf16x8*)(sX3 + (mrow + lr)*136 + kb*32 + quad*8);
        #pragma unroll
        for (int nt = 0; nt < 10; nt++) {
            int n = nt*16 + lr;
            float bv = (n < 150) ? bun[n] : 0.f;
            f32x4 acc = (f32x4){bv, bv, bv, bv};
            #pragma unroll
            for (int kb = 0; kb < 4; kb++)
                acc = __builtin_amdgcn_mfma_f32_16x16x32_bf16(au[kb], WUv[(nt*4 + kb)*64 + l], acc, 0, 0, 0);
            if (n < 150) {
                #pragma unroll
                for (int r = 0; r < 4; r++) {
                    int row = gbase + mrow + quad*4 + r;
                    out[row*150 + n] = acc[r];
                }
            }
        }
    }
}

// ============================ launcher ======================================
extern "C" void kernel_launch(void* const* d_in, const int* in_sizes, int n_in,
                              void* d_out, int out_size, void* d_ws, size_t ws_size,
                              hipStream_t stream) {
    const int*   p_val = (const int*)d_in[0];
    const int*   a_tok = (const int*)d_in[1];
    const int*   b_tok = (const int*)d_in[2];
    const float* tok   = (const float*)d_in[3];
    const float* pos   = (const float*)d_in[4];
    const float* W_mem = (const float*)d_in[5];
    const float* b_mem = (const float*)d_in[6];
    const float* W_sur = (const float*)d_in[7];
    const float* b_sur = (const float*)d_in[8];
    const float* W_m2r = (const float*)d_in[9];
    const float* b_m2r = (const float*)d_in[10];
    const float* W_Q   = (const float*)d_in[11];
    const float* W_K   = (const float*)d_in[12];
    const float* W_V   = (const float*)d_in[13];
    const float* W_O   = (const float*)d_in[14];
    const float* W1    = (const float*)d_in[15];
    const float* b1    = (const float*)d_in[16];
    const float* W2    = (const float*)d_in[17];
    const float* b2    = (const float*)d_in[18];
    const float* WU    = (const float*)d_in[19];
    const float* bun   = (const float*)d_in[20];
    float* out = (float*)d_out;

    float* ws = (float*)d_ws;
    float* memvec = ws + OFF_MEMVEC;
    float* x3base = ws + OFF_X3BASE;
    float* Q3     = ws + OFF_Q3;
    float* KE     = ws + OFF_KE;
    float* KM     = ws + OFF_KM;
    float* KP     = ws + OFF_KP;
    float* EV     = ws + OFF_EV;
    float* MV     = ws + OFF_MV;
    float* PV     = ws + OFF_PV;
    float* OVE    = ws + OFF_OVE;
    float* OVP    = ws + OFF_OVP;
    float* M3     = ws + OFF_M3;
    __bf16* W1f   = (__bf16*)(ws + OFF_W1F);
    __bf16* W2f   = (__bf16*)(ws + OFF_W2F);
    __bf16* WUf   = (__bf16*)(ws + OFF_WUF);

    k_prep1<<<PMAX + 1, 128, 0, stream>>>(tok, pos, W_mem, b_mem, W_sur, b_sur,
                                          W_m2r, b_m2r, memvec, x3base);
    k_prep2<<<762, 128, 0, stream>>>(tok, pos, memvec, x3base, W_Q, W_K, W_V,
                                     KE, KM, KP, Q3, EV, MV, PV);
    k_prep3<<<380, 256, 0, stream>>>(EV, MV, PV, memvec, W_O, W1, W2, WU,
                                     OVE, OVP, M3, W1f, W2f, WUf);
    k_main<<<NBATCH/64, 256, 0, stream>>>(p_val, a_tok, b_tok,
                                          Q3, KE, KM, KP, OVE, OVP, M3, x3base,
                                          W1f, W2f, WUf, b1, b2, bun, out);
}

// Round 2
// 216.961 us; speedup vs baseline: 1.1579x; 1.1579x over previous
//
#include <hip/hip_runtime.h>

#define D      128
#define DM     64
#define DMLP   512
#define PMAX   150
#define VOC    152
#define EQT    151
#define NBATCH 65536

typedef __attribute__((ext_vector_type(8))) __bf16 bf16x8;
typedef __attribute__((ext_vector_type(4))) float  f32x4;

__device__ __forceinline__ float silu_f(float x){ return x / (1.0f + expf(-x)); }

// ---- workspace layout (float-slot offsets, all 16B-aligned) ----
#define OFF_MEMVEC 0        // 150*128 f32
#define OFF_X3BASE 19200    // 128 f32
#define OFF_Q3     19328    // 150*128 f32
#define OFF_KE     38528    // 152*128 f32
#define OFF_KP     57984    // 4*128 f32
#define OFF_EV     58496    // 152*128 f32
#define OFF_PV     77952    // 4*128 f32
#define OFF_MV     78464    // 150*128 f32
#define OFF_SC     97664    // 150*156*4 f32 (score table, KP/diag entries at v=152..155)
#define OFF_O0     191264   // 150*512 bf16  (OVE[p]+OVP[0], per-head)
#define OFF_O1     229664   // 150*512 bf16  (OVE[v]+OVP[1])
#define OFF_O2     268064   // 150*512 bf16  (OVE[v]+OVP[2])
#define OFF_O3     306464   // 512 bf16      (OVE[EQT]+OVP[3])
#define OFF_M3B    306720   // 150*128 bf16  (x3base + memvec + MV@W_O)
#define OFF_W1F    316320   // 65536 bf16 frag-packed
#define OFF_W2F    349088   // 65536 bf16
#define OFF_WUF    381856   // 20480 bf16

// ============ K_A: memvec + x3base + weight fragment repack (225 blocks) ====
__global__ void k_A(const float* __restrict__ tok, const float* __restrict__ pos,
                    const float* __restrict__ W_mem, const float* __restrict__ b_mem,
                    const float* __restrict__ W_sur, const float* __restrict__ b_sur,
                    const float* __restrict__ W_m2r, const float* __restrict__ b_m2r,
                    const float* __restrict__ W1, const float* __restrict__ W2,
                    const float* __restrict__ WU,
                    float* __restrict__ memvec, float* __restrict__ x3base,
                    __bf16* __restrict__ W1f, __bf16* __restrict__ W2f, __bf16* __restrict__ WUf)
{
    int r = blockIdx.x, t = threadIdx.x;
    if (r < PMAX) {
        int p = r;
        __shared__ float sx0[D], sz[DM], sdiff[D], szu[DM];
        if (t < D) sx0[t] = tok[p*D + t] + pos[t];
        __syncthreads();
        if (t < DM) {
            float acc = b_mem[t];
            for (int d = 0; d < D; d++) acc += sx0[d] * W_mem[d*DM + t];
            sz[t] = silu_f(acc);
        }
        __syncthreads();
        if (t < D) {
            float acc = b_sur[t];
            for (int j = 0; j < DM; j++) acc += sz[j] * W_sur[j*D + t];
            sdiff[t] = sx0[t] - acc;
        }
        __syncthreads();
        if (t < DM) {
            float acc = 0.f;
            for (int d = 0; d < D; d++) acc += sdiff[d] * W_mem[d*DM + t];
            szu[t] = sz[t] + silu_f(acc);
        }
        __syncthreads();
        if (t < D) {
            float acc = b_m2r[t];
            for (int j = 0; j < DM; j++) acc += szu[j] * W_m2r[j*D + t];
            memvec[p*D + t] = acc;
        }
    } else if (r == PMAX) {
        if (t < D) x3base[t] = tok[EQT*D + t] + pos[3*D + t];
    } else if (r < 183) {
        int f = (r-151)*256 + t;                       // W1 128x512
        int l = f & 63, kb = (f>>6) & 3, nb = f >> 8;
        int k0 = kb*32 + (l>>4)*8, n = nb*16 + (l&15);
        #pragma unroll
        for (int j = 0; j < 8; j++) W1f[f*8 + j] = (__bf16)W1[(k0+j)*DMLP + n];
    } else if (r < 215) {
        int f = (r-183)*256 + t;                       // W2 512x128
        int l = f & 63, kb = (f>>6) & 15, nb = f >> 10;
        int k0 = kb*32 + (l>>4)*8, n = nb*16 + (l&15);
        #pragma unroll
        for (int j = 0; j < 8; j++) W2f[f*8 + j] = (__bf16)W2[(k0+j)*D + n];
    } else {
        int f = (r-215)*256 + t;                       // W_un 128x150 (N pad 160)
        int l = f & 63, kb = (f>>6) & 3, nb = f >> 8;
        int k0 = kb*32 + (l>>4)*8, n = nb*16 + (l&15);
        #pragma unroll
        for (int j = 0; j < 8; j++) WUf[f*8 + j] = (__bf16)((n < 150) ? WU[(k0+j)*150 + n] : 0.f);
    }
}

// ============ K_B: projections (612 blocks x 128) ===========================
__global__ void k_B(const float* __restrict__ tok, const float* __restrict__ pos,
                    const float* __restrict__ memvec, const float* __restrict__ x3base,
                    const float* __restrict__ W_Q, const float* __restrict__ W_K,
                    const float* __restrict__ W_V,
                    float* __restrict__ KE, float* __restrict__ KP, float* __restrict__ Q3,
                    float* __restrict__ EV, float* __restrict__ MV, float* __restrict__ PV)
{
    int r = blockIdx.x, t = threadIdx.x;
    const float* src; const float* add = nullptr; const float* W; float* outp;
    if      (r < 152) { src = tok    + r*D;                     W = W_K; outp = KE + r*D; }
    else if (r < 156) { src = pos    + (r-152)*D;               W = W_K; outp = KP + (r-152)*D; }
    else if (r < 306) { src = memvec + (r-156)*D; add = x3base; W = W_Q; outp = Q3 + (r-156)*D; }
    else if (r < 458) { src = tok    + (r-306)*D;               W = W_V; outp = EV + (r-306)*D; }
    else if (r < 608) { src = memvec + (r-458)*D;               W = W_V; outp = MV + (r-458)*D; }
    else              { src = pos    + (r-608)*D;               W = W_V; outp = PV + (r-608)*D; }
    __shared__ float s[D];
    s[t] = src[t] + (add ? add[t] : 0.f);
    __syncthreads();
    int h = t >> 5, k = t & 31;
    float acc = 0.f;
    for (int d = 0; d < D; d++) acc += s[d] * W[h*4096 + d*32 + k];
    outp[t] = acc;
}

// ============ K_C: folded OV tables + M3b + score table (751 blocks x 256) ==
__global__ void k_C(const float* __restrict__ EV, const float* __restrict__ PV,
                    const float* __restrict__ MV, const float* __restrict__ memvec,
                    const float* __restrict__ x3base,
                    const float* __restrict__ Q3, const float* __restrict__ KE,
                    const float* __restrict__ KP, const float* __restrict__ W_O,
                    __bf16* __restrict__ O0, __bf16* __restrict__ O1,
                    __bf16* __restrict__ O2, __bf16* __restrict__ O3,
                    __bf16* __restrict__ M3B, float* __restrict__ SC)
{
    int r = blockIdx.x, t = threadIdx.x;
    if (r <= 450) {
        // folded OV tables: (EV[v]+PV[tt]) per-head @ W_O
        int tt, v; __bf16* outp;
        if (r < 150)      { tt = 0; v = r;       outp = O0 + v*512; }
        else if (r < 300) { tt = 1; v = r - 150; outp = O1 + v*512; }
        else if (r < 450) { tt = 2; v = r - 300; outp = O2 + v*512; }
        else              { tt = 3; v = EQT;     outp = O3; }
        __shared__ float sv[D];
        if (t < D) sv[t] = EV[v*D + t] + PV[tt*D + t];
        __syncthreads();
        #pragma unroll
        for (int i = 0; i < 2; i++) {
            int c = t + i*256;
            int h = c >> 7, m = c & 127;
            float acc = 0.f;
            for (int k = 0; k < 32; k++) acc += sv[h*32 + k] * W_O[h*4096 + k*128 + m];
            outp[c] = (__bf16)acc;
        }
    } else if (r < 601) {
        // M3b[p] = bf16( x3base + memvec[p] + MV[p] @ W_O )
        int p = r - 451;
        __shared__ float s2[D];
        if (t < D) s2[t] = MV[p*D + t];
        __syncthreads();
        if (t < D) {
            float acc = memvec[p*D + t] + x3base[t];
            for (int c = 0; c < D; c++) acc += s2[c] * W_O[c*D + t];
            M3B[p*D + t] = (__bf16)acc;
        }
    } else {
        // SC[p][v][h]: v<152 -> scale*Q3h.KEh[v]; 152: t0 diag; 153: t3; 154/155: KP1/2
        int p = r - 601;
        const float scale = 0.17677669529663687f;  // 1/sqrt(32)
        __shared__ float q[D];
        if (t < D) q[t] = Q3[p*D + t];
        __syncthreads();
        for (int i = t; i < 624; i += 256) {
            int v = i >> 2, h = i & 3;
            const float* qh = q + h*32;
            float acc = 0.f;
            if (v < 152) {
                const float* ke = KE + v*D + h*32;
                for (int k = 0; k < 32; k++) acc += qh[k] * ke[k];
            } else if (v == 152) {
                const float* ke = KE + p*D + h*32; const float* kp = KP + 0*D + h*32;
                for (int k = 0; k < 32; k++) acc += qh[k] * (ke[k] + kp[k]);
            } else if (v == 153) {
                const float* ke = KE + EQT*D + h*32; const float* kp = KP + 3*D + h*32;
                for (int k = 0; k < 32; k++) acc += qh[k] * (ke[k] + kp[k]);
            } else if (v == 154) {
                const float* kp = KP + 1*D + h*32;
                for (int k = 0; k < 32; k++) acc += qh[k] * kp[k];
            } else {
                const float* kp = KP + 2*D + h*32;
                for (int k = 0; k < 32; k++) acc += qh[k] * kp[k];
            }
            SC[p*624 + i] = acc * scale;
        }
    }
}

// ============ K_main2: fused attention + MLP + unembed (1024 x 256) =========
__global__ __launch_bounds__(256, 4) void k_main2(
    const int* __restrict__ p_val, const int* __restrict__ a_tok, const int* __restrict__ b_tok,
    const float* __restrict__ SC, const __bf16* __restrict__ O0, const __bf16* __restrict__ O1,
    const __bf16* __restrict__ O2, const __bf16* __restrict__ O3g, const __bf16* __restrict__ M3B,
    const __bf16* __restrict__ W1f, const __bf16* __restrict__ W2f, const __bf16* __restrict__ WUf,
    const float* __restrict__ b1, const float* __restrict__ b2, const float* __restrict__ bun,
    float* __restrict__ out)
{
    __shared__ __align__(16) __bf16 sX3[64*136];   // 17408 B
    __shared__ __align__(16) __bf16 sH [64*136];   // 17408 B
    __shared__ __align__(16) float  sW [64*16];    //  4096 B
    __shared__ __align__(16) __bf16 sO3[512];      //  1024 B  => 39936 B total

    int tid = threadIdx.x;
    int gbase = blockIdx.x * 64;

    for (int i = tid; i < 512; i += 256) sO3[i] = O3g[i];
    __syncthreads();

    // ---------- phase 1a: scores from table + softmax (thread=(sample,head))
    {
        int s = tid >> 2, h = tid & 3;
        int gs = gbase + s;
        int p = p_val[gs], ta = a_tok[gs], tb = b_tok[gs];
        const float* SCp = SC + p*624;
        float s0 = SCp[152*4 + h];
        float s3 = SCp[153*4 + h];
        float s1 = SCp[ta*4 + h] + SCp[154*4 + h];
        float s2 = SCp[tb*4 + h] + SCp[155*4 + h];
        float mx = fmaxf(fmaxf(s0, s1), fmaxf(s2, s3));
        float e0 = expf(s0-mx), e1 = expf(s1-mx), e2 = expf(s2-mx), e3 = expf(s3-mx);
        float inv = 1.f / (e0 + e1 + e2 + e3);
        sW[s*16 + h*4 + 0] = e0*inv; sW[s*16 + h*4 + 1] = e1*inv;
        sW[s*16 + h*4 + 2] = e2*inv; sW[s*16 + h*4 + 3] = e3*inv;
    }
    __syncthreads();

    // ---------- phase 1b: x3 = M3b[p] + weighted bf16 OV tables -------------
    {
        int s = tid >> 2, q = tid & 3;
        int gs = gbase + s;
        int p = p_val[gs], ta = a_tok[gs], tb = b_tok[gs];
        float w[16];
        #pragma unroll
        for (int i = 0; i < 16; i++) w[i] = sW[s*16 + i];
        const bf16x8* m3v = (const bf16x8*)(M3B + p*128);
        const bf16x8* t0  = (const bf16x8*)(O0 + p*512);
        const bf16x8* t1  = (const bf16x8*)(O1 + ta*512);
        const bf16x8* t2  = (const bf16x8*)(O2 + tb*512);
        const bf16x8* t3  = (const bf16x8*)sO3;
        #pragma unroll
        for (int j = 0; j < 4; j++) {
            int c8 = q*4 + j;                  // bf16x8 index within 128-col row
            bf16x8 mv = m3v[c8];
            float v[8];
            #pragma unroll
            for (int e = 0; e < 8; e++) v[e] = (float)mv[e];
            #pragma unroll
            for (int h = 0; h < 4; h++) {
                int o8 = h*16 + c8;            // within 512-col per-head row
                bf16x8 e0 = t0[o8], e1 = t1[o8], e2 = t2[o8], e3 = t3[o8];
                float w0 = w[h*4+0], w1 = w[h*4+1], w2 = w[h*4+2], w3 = w[h*4+3];
                #pragma unroll
                for (int e = 0; e < 8; e++)
                    v[e] += w0*(float)e0[e] + w1*(float)e1[e] + w2*(float)e2[e] + w3*(float)e3[e];
            }
            bf16x8 st;
            #pragma unroll
            for (int e = 0; e < 8; e++) st[e] = (__bf16)v[e];
            *(bf16x8*)(sX3 + s*136 + q*32 + j*8) = st;
        }
    }
    __syncthreads();

    // ---------- phase 2: MFMA MLP (4 chunks of 128 hidden) + unembed --------
    {
        int wv = tid >> 6, l = tid & 63;
        int lr = l & 15, quad = l >> 4;
        int mrow = wv * 16;
        const bf16x8* W1v = (const bf16x8*)W1f;
        const bf16x8* W2v = (const bf16x8*)W2f;
        const bf16x8* WUv = (const bf16x8*)WUf;

        bf16x8 a[4];
        #pragma unroll
        for (int kb = 0; kb < 4; kb++)
            a[kb] = *(const bf16x8*)(sX3 + (mrow + lr)*136 + kb*32 + quad*8);

        f32x4 acc2[8];
        #pragma unroll
        for (int i = 0; i < 8; i++) acc2[i] = (f32x4){0.f, 0.f, 0.f, 0.f};

        for (int cc = 0; cc < 4; cc++) {
            #pragma unroll
            for (int nb = 0; nb < 8; nb++) {
                int nbg = cc*8 + nb;
                int n = nbg*16 + lr;
                float bv = b1[n];
                f32x4 acc = (f32x4){bv, bv, bv, bv};
                #pragma unroll
                for (int kb = 0; kb < 4; kb++)
                    acc = __builtin_amdgcn_mfma_f32_16x16x32_bf16(a[kb], W1v[(nbg*4 + kb)*64 + l], acc, 0, 0, 0);
                int colbase = nb*16 + lr;
                #pragma unroll
                for (int r = 0; r < 4; r++)
                    sH[(mrow + quad*4 + r)*136 + colbase] = (__bf16)fmaxf(acc[r], 0.f);
            }
            __syncthreads();
            #pragma unroll
            for (int kb2 = 0; kb2 < 4; kb2++) {
                bf16x8 a2 = *(const bf16x8*)(sH + (mrow + lr)*136 + kb2*32 + quad*8);
                int kbg = cc*4 + kb2;
                #pragma unroll
                for (int nb2 = 0; nb2 < 8; nb2++)
                    acc2[nb2] = __builtin_amdgcn_mfma_f32_16x16x32_bf16(a2, W2v[(nb2*16 + kbg)*64 + l], acc2[nb2], 0, 0, 0);
            }
            __syncthreads();
        }

        // finalize x3'' = x3 + mlp_out + b2
        #pragma unroll
        for (int nb2 = 0; nb2 < 8; nb2++) {
            int n = nb2*16 + lr;
            #pragma unroll
            for (int r = 0; r < 4; r++) {
                int row = mrow + quad*4 + r;
                float v = acc2[nb2][r] + b2[n] + (float)sX3[row*136 + n];
                sX3[row*136 + n] = (__bf16)v;
            }
        }
        __syncthreads();

        // unembed
        bf16x8 au[4];
        #pragma unroll
        for (int kb = 0; kb < 4; kb++)
            au[kb] = *(const bf16x8*)(sX3 + (mrow + lr)*136 + kb*32 + quad*8);
        #pragma unroll
        for (int nt = 0; nt < 10; nt++) {
            int n = nt*16 + lr;
            float bv = (n < 150) ? bun[n] : 0.f;
            f32x4 acc = (f32x4){bv, bv, bv, bv};
            #pragma unroll
            for (int kb = 0; kb < 4; kb++)
                acc = __builtin_amdgcn_mfma_f32_16x16x32_bf16(au[kb], WUv[(nt*4 + kb)*64 + l], acc, 0, 0, 0);
            if (n < 150) {
                #pragma unroll
                for (int r = 0; r < 4; r++) {
                    int row = gbase + mrow + quad*4 + r;
                    out[row*150 + n] = acc[r];
                }
            }
        }
    }
}

// ============================ launcher ======================================
extern "C" void kernel_launch(void* const* d_in, const int* in_sizes, int n_in,
                              void* d_out, int out_size, void* d_ws, size_t ws_size,
                              hipStream_t stream) {
    const int*   p_val = (const int*)d_in[0];
    const int*   a_tok = (const int*)d_in[1];
    const int*   b_tok = (const int*)d_in[2];
    const float* tok   = (const float*)d_in[3];
    const float* pos   = (const float*)d_in[4];
    const float* W_mem = (const float*)d_in[5];
    const float* b_mem = (const float*)d_in[6];
    const float* W_sur = (const float*)d_in[7];
    const float* b_sur = (const float*)d_in[8];
    const float* W_m2r = (const float*)d_in[9];
    const float* b_m2r = (const float*)d_in[10];
    const float* W_Q   = (const float*)d_in[11];
    const float* W_K   = (const float*)d_in[12];
    const float* W_V   = (const float*)d_in[13];
    const float* W_O   = (const float*)d_in[14];
    const float* W1    = (const float*)d_in[15];
    const float* b1    = (const float*)d_in[16];
    const float* W2    = (const float*)d_in[17];
    const float* b2    = (const float*)d_in[18];
    const float* WU    = (const float*)d_in[19];
    const float* bun   = (const float*)d_in[20];
    float* out = (float*)d_out;

    float* ws = (float*)d_ws;
    float* memvec = ws + OFF_MEMVEC;
    float* x3base = ws + OFF_X3BASE;
    float* Q3     = ws + OFF_Q3;
    float* KE     = ws + OFF_KE;
    float* KP     = ws + OFF_KP;
    float* EV     = ws + OFF_EV;
    float* PV     = ws + OFF_PV;
    float* MV     = ws + OFF_MV;
    float* SC     = ws + OFF_SC;
    __bf16* O0    = (__bf16*)(ws + OFF_O0);
    __bf16* O1    = (__bf16*)(ws + OFF_O1);
    __bf16* O2    = (__bf16*)(ws + OFF_O2);
    __bf16* O3    = (__bf16*)(ws + OFF_O3);
    __bf16* M3B   = (__bf16*)(ws + OFF_M3B);
    __bf16* W1f   = (__bf16*)(ws + OFF_W1F);
    __bf16* W2f   = (__bf16*)(ws + OFF_W2F);
    __bf16* WUf   = (__bf16*)(ws + OFF_WUF);

    k_A<<<225, 256, 0, stream>>>(tok, pos, W_mem, b_mem, W_sur, b_sur, W_m2r, b_m2r,
                                 W1, W2, WU, memvec, x3base, W1f, W2f, WUf);
    k_B<<<612, 128, 0, stream>>>(tok, pos, memvec, x3base, W_Q, W_K, W_V,
                                 KE, KP, Q3, EV, MV, PV);
    k_C<<<751, 256, 0, stream>>>(EV, PV, MV, memvec, x3base, Q3, KE, KP, W_O,
                                 O0, O1, O2, O3, M3B, SC);
    k_main2<<<NBATCH/64, 256, 0, stream>>>(p_val, a_tok, b_tok, SC, O0, O1, O2, O3, M3B,
                                           W1f, W2f, WUf, b1, b2, bun, out);
}

// Round 3
// 213.046 us; speedup vs baseline: 1.1792x; 1.0184x over previous
//
#include <hip/hip_runtime.h>

#define D      128
#define DM     64
#define DMLP   512
#define PMAX   150
#define VOC    152
#define EQT    151
#define NBATCH 65536

typedef __attribute__((ext_vector_type(8))) __bf16 bf16x8;
typedef __attribute__((ext_vector_type(4))) float  f32x4;

__device__ __forceinline__ float silu_f(float x){ return x / (1.0f + expf(-x)); }

// ---- workspace layout (float-slot offsets) ----
#define OFF_MEMVEC 0        // 150*128 f32
#define OFF_X3BASE 19200    // 128 f32
#define OFF_KE     19328    // 152*128 f32
#define OFF_KP     38784    // 4*128 f32
#define OFF_SC     39296    // 150*624 f32
#define OFF_O0     132896   // 150*512 bf16
#define OFF_O1     171296   // 150*512 bf16
#define OFF_O2     209696   // 150*512 bf16
#define OFF_O3     248096   // 512 bf16
#define OFF_M3B    248352   // 150*128 bf16
#define OFF_W1F    257952   // 65536 bf16 frag-packed
#define OFF_W2F    290720   // 65536 bf16
#define OFF_WUF    323488   // 20480 bf16

// ===== P1: token-side tables + O-tables + memvec + weight repack (832 blocks x 256)
__global__ void k_P1(const float* __restrict__ tok, const float* __restrict__ pos,
                     const float* __restrict__ W_mem, const float* __restrict__ b_mem,
                     const float* __restrict__ W_sur, const float* __restrict__ b_sur,
                     const float* __restrict__ W_m2r, const float* __restrict__ b_m2r,
                     const float* __restrict__ W_K, const float* __restrict__ W_V,
                     const float* __restrict__ W_O,
                     const float* __restrict__ W1, const float* __restrict__ W2,
                     const float* __restrict__ WU,
                     float* __restrict__ memvec, float* __restrict__ x3base,
                     float* __restrict__ KE, float* __restrict__ KP,
                     __bf16* __restrict__ O0, __bf16* __restrict__ O1,
                     __bf16* __restrict__ O2, __bf16* __restrict__ O3,
                     __bf16* __restrict__ W1f, __bf16* __restrict__ W2f, __bf16* __restrict__ WUf)
{
    int r = blockIdx.x, t = threadIdx.x;
    if (r < 150) {
        // memvec[p]: 4-stage silu chain
        int p = r;
        __shared__ float sx0[D], sz[DM], sdiff[D], szu[DM];
        if (t < D) sx0[t] = tok[p*D + t] + pos[t];
        __syncthreads();
        if (t < DM) {
            float acc = b_mem[t];
            for (int d = 0; d < D; d++) acc += sx0[d] * W_mem[d*DM + t];
            sz[t] = silu_f(acc);
        }
        __syncthreads();
        if (t < D) {
            float acc = b_sur[t];
            for (int j = 0; j < DM; j++) acc += sz[j] * W_sur[j*D + t];
            sdiff[t] = sx0[t] - acc;
        }
        __syncthreads();
        if (t < DM) {
            float acc = 0.f;
            for (int d = 0; d < D; d++) acc += sdiff[d] * W_mem[d*DM + t];
            szu[t] = sz[t] + silu_f(acc);
        }
        __syncthreads();
        if (t < D) {
            float acc = b_m2r[t];
            for (int j = 0; j < DM; j++) acc += szu[j] * W_m2r[j*D + t];
            memvec[p*D + t] = acc;
        }
    } else if (r == 150) {
        if (t < D) x3base[t] = tok[EQT*D + t] + pos[3*D + t];
    } else if (r < 307) {
        // KE rows (152) + KP rows (4)
        int idx = r - 151;
        const float* src = (idx < 152) ? (tok + idx*D) : (pos + (idx-152)*D);
        float*       dst = (idx < 152) ? (KE + idx*D)  : (KP + (idx-152)*D);
        __shared__ float s[D];
        if (t < D) s[t] = src[t];
        __syncthreads();
        if (t < D) {
            int h = t >> 5, k = t & 31;
            float acc = 0.f;
            for (int d = 0; d < D; d++) acc += s[d] * W_K[h*4096 + d*32 + k];
            dst[t] = acc;
        }
    } else if (r < 758) {
        // folded OV tables with inline V-projection: (tok[v]+pos[tt]) @ W_V @ W_O per head
        int idx = r - 307;
        int tt, v; __bf16* outp;
        if (idx < 150)      { tt = 0; v = idx;       outp = O0 + v*512; }
        else if (idx < 300) { tt = 1; v = idx - 150; outp = O1 + (idx-150)*512; }
        else if (idx < 450) { tt = 2; v = idx - 300; outp = O2 + (idx-300)*512; }
        else                { tt = 3; v = EQT;       outp = O3; }
        __shared__ float sTP[D], sv[D];
        if (t < D) sTP[t] = tok[v*D + t] + pos[tt*D + t];
        __syncthreads();
        if (t < D) {
            int h = t >> 5, k = t & 31;
            float acc = 0.f;
            for (int d = 0; d < D; d++) acc += sTP[d] * W_V[h*4096 + d*32 + k];
            sv[t] = acc;
        }
        __syncthreads();
        #pragma unroll
        for (int i = 0; i < 2; i++) {
            int c = t + i*256;
            int h = c >> 7, m = c & 127;
            float acc = 0.f;
            for (int k = 0; k < 32; k++) acc += sv[h*32 + k] * W_O[h*4096 + k*128 + m];
            outp[c] = (__bf16)acc;
        }
    } else if (r < 790) {
        int f = (r-758)*256 + t;                       // W1 128x512
        int l = f & 63, kb = (f>>6) & 3, nb = f >> 8;
        int k0 = kb*32 + (l>>4)*8, n = nb*16 + (l&15);
        #pragma unroll
        for (int j = 0; j < 8; j++) W1f[f*8 + j] = (__bf16)W1[(k0+j)*DMLP + n];
    } else if (r < 822) {
        int f = (r-790)*256 + t;                       // W2 512x128
        int l = f & 63, kb = (f>>6) & 15, nb = f >> 10;
        int k0 = kb*32 + (l>>4)*8, n = nb*16 + (l&15);
        #pragma unroll
        for (int j = 0; j < 8; j++) W2f[f*8 + j] = (__bf16)W2[(k0+j)*D + n];
    } else {
        int f = (r-822)*256 + t;                       // W_un 128x150 (N pad 160)
        int l = f & 63, kb = (f>>6) & 3, nb = f >> 8;
        int k0 = kb*32 + (l>>4)*8, n = nb*16 + (l&15);
        #pragma unroll
        for (int j = 0; j < 8; j++) WUf[f*8 + j] = (__bf16)((n < 150) ? WU[(k0+j)*150 + n] : 0.f);
    }
}

// ===== P2: per-p tables — Q3 (inline), SC score table, M3B (150 blocks x 256)
__global__ void k_P2(const float* __restrict__ memvec, const float* __restrict__ x3base,
                     const float* __restrict__ W_Q, const float* __restrict__ W_V,
                     const float* __restrict__ W_O,
                     const float* __restrict__ KE, const float* __restrict__ KP,
                     float* __restrict__ SC, __bf16* __restrict__ M3B)
{
    int p = blockIdx.x, t = threadIdx.x;
    __shared__ float sMem[D], sIn[D], sQ3[D], sMV[D];
    if (t < D) { float m = memvec[p*D + t]; sMem[t] = m; sIn[t] = m + x3base[t]; }
    __syncthreads();
    if (t < D) {
        int h = t >> 5, k = t & 31;
        float acc = 0.f;
        for (int d = 0; d < D; d++) acc += sIn[d] * W_Q[h*4096 + d*32 + k];
        sQ3[t] = acc;
    } else {
        int c = t - D; int h = c >> 5, k = c & 31;
        float acc = 0.f;
        for (int d = 0; d < D; d++) acc += sMem[d] * W_V[h*4096 + d*32 + k];
        sMV[c] = acc;
    }
    __syncthreads();
    const float scale = 0.17677669529663687f;  // 1/sqrt(32)
    for (int i = t; i < 624; i += 256) {
        int v = i >> 2, h = i & 3;
        const float* qh = sQ3 + h*32;
        float acc = 0.f;
        if (v < 152) {
            const float* ke = KE + v*D + h*32;
            for (int k = 0; k < 32; k++) acc += qh[k] * ke[k];
        } else if (v == 152) {
            const float* ke = KE + p*D + h*32; const float* kp = KP + h*32;
            for (int k = 0; k < 32; k++) acc += qh[k] * (ke[k] + kp[k]);
        } else if (v == 153) {
            const float* ke = KE + EQT*D + h*32; const float* kp = KP + 3*D + h*32;
            for (int k = 0; k < 32; k++) acc += qh[k] * (ke[k] + kp[k]);
        } else if (v == 154) {
            const float* kp = KP + 1*D + h*32;
            for (int k = 0; k < 32; k++) acc += qh[k] * kp[k];
        } else {
            const float* kp = KP + 2*D + h*32;
            for (int k = 0; k < 32; k++) acc += qh[k] * kp[k];
        }
        SC[p*624 + i] = acc * scale;
    }
    if (t < D) {
        float acc = sIn[t];
        for (int c = 0; c < D; c++) acc += sMV[c] * W_O[c*D + t];
        M3B[p*D + t] = (__bf16)acc;
    }
}

// ===== main: single-wave blocks, 16 samples each (4096 blocks x 64) =========
__global__ __launch_bounds__(64, 4) void k_main3(
    const int* __restrict__ p_val, const int* __restrict__ a_tok, const int* __restrict__ b_tok,
    const float* __restrict__ SC, const __bf16* __restrict__ O0, const __bf16* __restrict__ O1,
    const __bf16* __restrict__ O2, const __bf16* __restrict__ O3g, const __bf16* __restrict__ M3B,
    const __bf16* __restrict__ W1f, const __bf16* __restrict__ W2f, const __bf16* __restrict__ WUf,
    const float* __restrict__ b1, const float* __restrict__ b2, const float* __restrict__ bun,
    float* __restrict__ out)
{
    __shared__ __align__(16) __bf16 sX3[16*136];   // 4352 B
    __shared__ __align__(16) __bf16 sH [16*136];   // 4352 B
    __shared__ __align__(16) float  sW [16*17];    // 1088 B  => 9792 B total

    int tid = threadIdx.x;
    int gbase = blockIdx.x * 16;
    int s = tid >> 2, hq = tid & 3;         // (sample, head) / (sample, quarter)
    int gs = gbase + s;
    int p = p_val[gs], ta = a_tok[gs], tb = b_tok[gs];

    // ---------- phase 1a: scores from table + softmax -----------------------
    {
        const float* SCp = SC + p*624;
        float s0 = SCp[608 + hq];
        float s3 = SCp[612 + hq];
        float s1 = SCp[ta*4 + hq] + SCp[616 + hq];
        float s2 = SCp[tb*4 + hq] + SCp[620 + hq];
        float mx = fmaxf(fmaxf(s0, s1), fmaxf(s2, s3));
        float e0 = expf(s0-mx), e1 = expf(s1-mx), e2 = expf(s2-mx), e3 = expf(s3-mx);
        float inv = 1.f / (e0 + e1 + e2 + e3);
        sW[s*17 + hq*4 + 0] = e0*inv; sW[s*17 + hq*4 + 1] = e1*inv;
        sW[s*17 + hq*4 + 2] = e2*inv; sW[s*17 + hq*4 + 3] = e3*inv;
    }
    __syncthreads();

    // ---------- phase 1b: x3 = M3b[p] + weighted bf16 OV tables -------------
    {
        float w[16];
        #pragma unroll
        for (int i = 0; i < 16; i++) w[i] = sW[s*17 + i];
        const bf16x8* m3v = (const bf16x8*)(M3B + p*128);
        const bf16x8* t0  = (const bf16x8*)(O0 + p*512);
        const bf16x8* t1  = (const bf16x8*)(O1 + ta*512);
        const bf16x8* t2  = (const bf16x8*)(O2 + tb*512);
        const bf16x8* t3  = (const bf16x8*)O3g;
        #pragma unroll
        for (int j = 0; j < 4; j++) {
            int c8 = hq*4 + j;
            bf16x8 mv = m3v[c8];
            float v[8];
            #pragma unroll
            for (int e = 0; e < 8; e++) v[e] = (float)mv[e];
            #pragma unroll
            for (int h = 0; h < 4; h++) {
                int o8 = h*16 + c8;
                bf16x8 e0 = t0[o8], e1 = t1[o8], e2 = t2[o8], e3 = t3[o8];
                float w0 = w[h*4+0], w1 = w[h*4+1], w2 = w[h*4+2], w3 = w[h*4+3];
                #pragma unroll
                for (int e = 0; e < 8; e++)
                    v[e] += w0*(float)e0[e] + w1*(float)e1[e] + w2*(float)e2[e] + w3*(float)e3[e];
            }
            bf16x8 st;
            #pragma unroll
            for (int e = 0; e < 8; e++) st[e] = (__bf16)v[e];
            *(bf16x8*)(sX3 + s*136 + hq*32 + j*8) = st;
        }
    }
    __syncthreads();

    // ---------- phase 2: MFMA MLP (4 chunks of 128 hidden) + unembed --------
    {
        int l = tid, lr = l & 15, quad = l >> 4;
        const bf16x8* W1v = (const bf16x8*)W1f;
        const bf16x8* W2v = (const bf16x8*)W2f;
        const bf16x8* WUv = (const bf16x8*)WUf;

        bf16x8 a[4];
        #pragma unroll
        for (int kb = 0; kb < 4; kb++)
            a[kb] = *(const bf16x8*)(sX3 + lr*136 + kb*32 + quad*8);

        f32x4 acc2[8];
        #pragma unroll
        for (int i = 0; i < 8; i++) acc2[i] = (f32x4){0.f, 0.f, 0.f, 0.f};

        for (int cc = 0; cc < 4; cc++) {
            #pragma unroll
            for (int nb = 0; nb < 8; nb++) {
                int nbg = cc*8 + nb;
                int n = nbg*16 + lr;
                float bv = b1[n];
                f32x4 acc = (f32x4){bv, bv, bv, bv};
                #pragma unroll
                for (int kb = 0; kb < 4; kb++)
                    acc = __builtin_amdgcn_mfma_f32_16x16x32_bf16(a[kb], W1v[(nbg*4 + kb)*64 + l], acc, 0, 0, 0);
                int colbase = nb*16 + lr;
                #pragma unroll
                for (int r = 0; r < 4; r++)
                    sH[(quad*4 + r)*136 + colbase] = (__bf16)fmaxf(acc[r], 0.f);
            }
            __syncthreads();   // single-wave: compiles to waitcnt, no cross-wave coupling
            #pragma unroll
            for (int kb2 = 0; kb2 < 4; kb2++) {
                bf16x8 a2 = *(const bf16x8*)(sH + lr*136 + kb2*32 + quad*8);
                int kbg = cc*4 + kb2;
                #pragma unroll
                for (int nb2 = 0; nb2 < 8; nb2++)
                    acc2[nb2] = __builtin_amdgcn_mfma_f32_16x16x32_bf16(a2, W2v[(nb2*16 + kbg)*64 + l], acc2[nb2], 0, 0, 0);
            }
            __syncthreads();
        }

        // finalize x3'' = x3 + mlp_out + b2
        #pragma unroll
        for (int nb2 = 0; nb2 < 8; nb2++) {
            int n = nb2*16 + lr;
            #pragma unroll
            for (int r = 0; r < 4; r++) {
                int row = quad*4 + r;
                float v = acc2[nb2][r] + b2[n] + (float)sX3[row*136 + n];
                sX3[row*136 + n] = (__bf16)v;
            }
        }
        __syncthreads();

        // unembed
        bf16x8 au[4];
        #pragma unroll
        for (int kb = 0; kb < 4; kb++)
            au[kb] = *(const bf16x8*)(sX3 + lr*136 + kb*32 + quad*8);
        #pragma unroll
        for (int nt = 0; nt < 10; nt++) {
            int n = nt*16 + lr;
            float bv = (n < 150) ? bun[n] : 0.f;
            f32x4 acc = (f32x4){bv, bv, bv, bv};
            #pragma unroll
            for (int kb = 0; kb < 4; kb++)
                acc = __builtin_amdgcn_mfma_f32_16x16x32_bf16(au[kb], WUv[(nt*4 + kb)*64 + l], acc, 0, 0, 0);
            if (n < 150) {
                #pragma unroll
                for (int r = 0; r < 4; r++) {
                    int row = gbase + quad*4 + r;
                    out[row*150 + n] = acc[r];
                }
            }
        }
    }
}

// ============================ launcher ======================================
extern "C" void kernel_launch(void* const* d_in, const int* in_sizes, int n_in,
                              void* d_out, int out_size, void* d_ws, size_t ws_size,
                              hipStream_t stream) {
    const int*   p_val = (const int*)d_in[0];
    const int*   a_tok = (const int*)d_in[1];
    const int*   b_tok = (const int*)d_in[2];
    const float* tok   = (const float*)d_in[3];
    const float* pos   = (const float*)d_in[4];
    const float* W_mem = (const float*)d_in[5];
    const float* b_mem = (const float*)d_in[6];
    const float* W_sur = (const float*)d_in[7];
    const float* b_sur = (const float*)d_in[8];
    const float* W_m2r = (const float*)d_in[9];
    const float* b_m2r = (const float*)d_in[10];
    const float* W_Q   = (const float*)d_in[11];
    const float* W_K   = (const float*)d_in[12];
    const float* W_V   = (const float*)d_in[13];
    const float* W_O   = (const float*)d_in[14];
    const float* W1    = (const float*)d_in[15];
    const float* b1    = (const float*)d_in[16];
    const float* W2    = (const float*)d_in[17];
    const float* b2    = (const float*)d_in[18];
    const float* WU    = (const float*)d_in[19];
    const float* bun   = (const float*)d_in[20];
    float* out = (float*)d_out;

    float* ws = (float*)d_ws;
    float* memvec = ws + OFF_MEMVEC;
    float* x3base = ws + OFF_X3BASE;
    float* KE     = ws + OFF_KE;
    float* KP     = ws + OFF_KP;
    float* SC     = ws + OFF_SC;
    __bf16* O0    = (__bf16*)(ws + OFF_O0);
    __bf16* O1    = (__bf16*)(ws + OFF_O1);
    __bf16* O2    = (__bf16*)(ws + OFF_O2);
    __bf16* O3    = (__bf16*)(ws + OFF_O3);
    __bf16* M3B   = (__bf16*)(ws + OFF_M3B);
    __bf16* W1f   = (__bf16*)(ws + OFF_W1F);
    __bf16* W2f   = (__bf16*)(ws + OFF_W2F);
    __bf16* WUf   = (__bf16*)(ws + OFF_WUF);

    k_P1<<<832, 256, 0, stream>>>(tok, pos, W_mem, b_mem, W_sur, b_sur, W_m2r, b_m2r,
                                  W_K, W_V, W_O, W1, W2, WU,
                                  memvec, x3base, KE, KP, O0, O1, O2, O3, W1f, W2f, WUf);
    k_P2<<<150, 256, 0, stream>>>(memvec, x3base, W_Q, W_V, W_O, KE, KP, SC, M3B);
    k_main3<<<NBATCH/16, 64, 0, stream>>>(p_val, a_tok, b_tok, SC, O0, O1, O2, O3, M3B,
                                          W1f, W2f, WUf, b1, b2, bun, out);
}

// Round 4
// 198.644 us; speedup vs baseline: 1.2647x; 1.0725x over previous
//
#include <hip/hip_runtime.h>

#define D      128
#define DM     64
#define DMLP   512
#define PMAX   150
#define VOC    152
#define EQT    151
#define NBATCH 65536

typedef __attribute__((ext_vector_type(8))) __bf16 bf16x8;
typedef __attribute__((ext_vector_type(4))) float  f32x4;

__device__ __forceinline__ float silu_f(float x){ return x / (1.0f + expf(-x)); }

// ---- workspace layout (float-slot offsets) ----
#define OFF_MEMVEC 0        // 150*128 f32
#define OFF_X3BASE 19200    // 128 f32
#define OFF_KE     19328    // 152*128 f32
#define OFF_KP     38784    // 4*128 f32
#define OFF_SC     39296    // 150*624 f32
#define OFF_O0     132896   // 150*512 bf16
#define OFF_O1     171296   // 150*512 bf16
#define OFF_O2     209696   // 150*512 bf16
#define OFF_O3     248096   // 512 bf16
#define OFF_M3B    248352   // 150*128 bf16
#define OFF_W1F    257952   // 65536 bf16 frag-packed
#define OFF_W2F    290720   // 65536 bf16
#define OFF_WUF    323488   // 20480 bf16

// ===== P1: token-side tables + O-tables + memvec + weight repack (832 blocks x 256)
__global__ void k_P1(const float* __restrict__ tok, const float* __restrict__ pos,
                     const float* __restrict__ W_mem, const float* __restrict__ b_mem,
                     const float* __restrict__ W_sur, const float* __restrict__ b_sur,
                     const float* __restrict__ W_m2r, const float* __restrict__ b_m2r,
                     const float* __restrict__ W_K, const float* __restrict__ W_V,
                     const float* __restrict__ W_O,
                     const float* __restrict__ W1, const float* __restrict__ W2,
                     const float* __restrict__ WU,
                     float* __restrict__ memvec, float* __restrict__ x3base,
                     float* __restrict__ KE, float* __restrict__ KP,
                     __bf16* __restrict__ O0, __bf16* __restrict__ O1,
                     __bf16* __restrict__ O2, __bf16* __restrict__ O3,
                     __bf16* __restrict__ W1f, __bf16* __restrict__ W2f, __bf16* __restrict__ WUf)
{
    int r = blockIdx.x, t = threadIdx.x;
    if (r < 150) {
        int p = r;
        __shared__ float sx0[D], sz[DM], sdiff[D], szu[DM];
        if (t < D) sx0[t] = tok[p*D + t] + pos[t];
        __syncthreads();
        if (t < DM) {
            float acc = b_mem[t];
            for (int d = 0; d < D; d++) acc += sx0[d] * W_mem[d*DM + t];
            sz[t] = silu_f(acc);
        }
        __syncthreads();
        if (t < D) {
            float acc = b_sur[t];
            for (int j = 0; j < DM; j++) acc += sz[j] * W_sur[j*D + t];
            sdiff[t] = sx0[t] - acc;
        }
        __syncthreads();
        if (t < DM) {
            float acc = 0.f;
            for (int d = 0; d < D; d++) acc += sdiff[d] * W_mem[d*DM + t];
            szu[t] = sz[t] + silu_f(acc);
        }
        __syncthreads();
        if (t < D) {
            float acc = b_m2r[t];
            for (int j = 0; j < DM; j++) acc += szu[j] * W_m2r[j*D + t];
            memvec[p*D + t] = acc;
        }
    } else if (r == 150) {
        if (t < D) x3base[t] = tok[EQT*D + t] + pos[3*D + t];
    } else if (r < 307) {
        int idx = r - 151;
        const float* src = (idx < 152) ? (tok + idx*D) : (pos + (idx-152)*D);
        float*       dst = (idx < 152) ? (KE + idx*D)  : (KP + (idx-152)*D);
        __shared__ float s[D];
        if (t < D) s[t] = src[t];
        __syncthreads();
        if (t < D) {
            int h = t >> 5, k = t & 31;
            float acc = 0.f;
            for (int d = 0; d < D; d++) acc += s[d] * W_K[h*4096 + d*32 + k];
            dst[t] = acc;
        }
    } else if (r < 758) {
        int idx = r - 307;
        int tt, v; __bf16* outp;
        if (idx < 150)      { tt = 0; v = idx;       outp = O0 + v*512; }
        else if (idx < 300) { tt = 1; v = idx - 150; outp = O1 + (idx-150)*512; }
        else if (idx < 450) { tt = 2; v = idx - 300; outp = O2 + (idx-300)*512; }
        else                { tt = 3; v = EQT;       outp = O3; }
        __shared__ float sTP[D], sv[D];
        if (t < D) sTP[t] = tok[v*D + t] + pos[tt*D + t];
        __syncthreads();
        if (t < D) {
            int h = t >> 5, k = t & 31;
            float acc = 0.f;
            for (int d = 0; d < D; d++) acc += sTP[d] * W_V[h*4096 + d*32 + k];
            sv[t] = acc;
        }
        __syncthreads();
        #pragma unroll
        for (int i = 0; i < 2; i++) {
            int c = t + i*256;
            int h = c >> 7, m = c & 127;
            float acc = 0.f;
            for (int k = 0; k < 32; k++) acc += sv[h*32 + k] * W_O[h*4096 + k*128 + m];
            outp[c] = (__bf16)acc;
        }
    } else if (r < 790) {
        int f = (r-758)*256 + t;                       // W1 128x512
        int l = f & 63, kb = (f>>6) & 3, nb = f >> 8;
        int k0 = kb*32 + (l>>4)*8, n = nb*16 + (l&15);
        #pragma unroll
        for (int j = 0; j < 8; j++) W1f[f*8 + j] = (__bf16)W1[(k0+j)*DMLP + n];
    } else if (r < 822) {
        int f = (r-790)*256 + t;                       // W2 512x128
        int l = f & 63, kb = (f>>6) & 15, nb = f >> 10;
        int k0 = kb*32 + (l>>4)*8, n = nb*16 + (l&15);
        #pragma unroll
        for (int j = 0; j < 8; j++) W2f[f*8 + j] = (__bf16)W2[(k0+j)*D + n];
    } else {
        int f = (r-822)*256 + t;                       // W_un 128x150 (N pad 160)
        int l = f & 63, kb = (f>>6) & 3, nb = f >> 8;
        int k0 = kb*32 + (l>>4)*8, n = nb*16 + (l&15);
        #pragma unroll
        for (int j = 0; j < 8; j++) WUf[f*8 + j] = (__bf16)((n < 150) ? WU[(k0+j)*150 + n] : 0.f);
    }
}

// ===== P2: per-p tables — Q3 (inline), SC score table, M3B (150 blocks x 256)
__global__ void k_P2(const float* __restrict__ memvec, const float* __restrict__ x3base,
                     const float* __restrict__ W_Q, const float* __restrict__ W_V,
                     const float* __restrict__ W_O,
                     const float* __restrict__ KE, const float* __restrict__ KP,
                     float* __restrict__ SC, __bf16* __restrict__ M3B)
{
    int p = blockIdx.x, t = threadIdx.x;
    __shared__ float sMem[D], sIn[D], sQ3[D], sMV[D];
    if (t < D) { float m = memvec[p*D + t]; sMem[t] = m; sIn[t] = m + x3base[t]; }
    __syncthreads();
    if (t < D) {
        int h = t >> 5, k = t & 31;
        float acc = 0.f;
        for (int d = 0; d < D; d++) acc += sIn[d] * W_Q[h*4096 + d*32 + k];
        sQ3[t] = acc;
    } else {
        int c = t - D; int h = c >> 5, k = c & 31;
        float acc = 0.f;
        for (int d = 0; d < D; d++) acc += sMem[d] * W_V[h*4096 + d*32 + k];
        sMV[c] = acc;
    }
    __syncthreads();
    const float scale = 0.17677669529663687f;
    for (int i = t; i < 624; i += 256) {
        int v = i >> 2, h = i & 3;
        const float* qh = sQ3 + h*32;
        float acc = 0.f;
        if (v < 152) {
            const float* ke = KE + v*D + h*32;
            for (int k = 0; k < 32; k++) acc += qh[k] * ke[k];
        } else if (v == 152) {
            const float* ke = KE + p*D + h*32; const float* kp = KP + h*32;
            for (int k = 0; k < 32; k++) acc += qh[k] * (ke[k] + kp[k]);
        } else if (v == 153) {
            const float* ke = KE + EQT*D + h*32; const float* kp = KP + 3*D + h*32;
            for (int k = 0; k < 32; k++) acc += qh[k] * (ke[k] + kp[k]);
        } else if (v == 154) {
            const float* kp = KP + 1*D + h*32;
            for (int k = 0; k < 32; k++) acc += qh[k] * kp[k];
        } else {
            const float* kp = KP + 2*D + h*32;
            for (int k = 0; k < 32; k++) acc += qh[k] * kp[k];
        }
        SC[p*624 + i] = acc * scale;
    }
    if (t < D) {
        float acc = sIn[t];
        for (int c = 0; c < D; c++) acc += sMV[c] * W_O[c*D + t];
        M3B[p*D + t] = (__bf16)acc;
    }
}

// ===== main: 512 blocks x 256 thr, 128 samples, LDS-resident weights ========
// smem: [0,40960) sWgt (x3-frags, then W1/W2 chunks, then WU)
//       [40960,59392) sHH (4 waves x 2 tiles x 16 x 72 bf16) / phase1 sWf
//       [59392,62592) sB (b1 512, b2 128, bun 160)
__global__ __launch_bounds__(256, 2) void k_mainM(
    const int* __restrict__ p_val, const int* __restrict__ a_tok, const int* __restrict__ b_tok,
    const float* __restrict__ SC, const __bf16* __restrict__ O0, const __bf16* __restrict__ O1,
    const __bf16* __restrict__ O2, const __bf16* __restrict__ O3g, const __bf16* __restrict__ M3B,
    const __bf16* __restrict__ W1f, const __bf16* __restrict__ W2f, const __bf16* __restrict__ WUf,
    const float* __restrict__ b1, const float* __restrict__ b2, const float* __restrict__ bun,
    float* __restrict__ out)
{
    __shared__ __align__(16) char smem[62592];
    char*   sWgt = smem;
    char*   sHH  = smem + 40960;
    float*  sWf  = (float*)(smem + 40960);
    float*  sB   = (float*)(smem + 59392);

    int tid = threadIdx.x;
    int gbase = blockIdx.x * 128;
    int wv = tid >> 6, l = tid & 63, lr = l & 15, quad = l >> 4;

    // stage biases
    for (int i = tid; i < 512; i += 256) sB[i] = b1[i];
    if (tid < 128) sB[512 + tid] = b2[tid];
    if (tid < 160) sB[640 + tid] = bun[tid];

    // ---------------- phase 1a: scores + softmax (thread = sample, 2 heads) --
    {
        int s = tid >> 1, half = tid & 1;
        int gs = gbase + s;
        int p = p_val[gs], ta = a_tok[gs], tb = b_tok[gs];
        const float* SCp = SC + p*624;
        #pragma unroll
        for (int hh = 0; hh < 2; hh++) {
            int h = half*2 + hh;
            float s0 = SCp[608 + h];
            float s3 = SCp[612 + h];
            float s1 = SCp[ta*4 + h] + SCp[616 + h];
            float s2 = SCp[tb*4 + h] + SCp[620 + h];
            float mx = fmaxf(fmaxf(s0, s1), fmaxf(s2, s3));
            float e0 = expf(s0-mx), e1 = expf(s1-mx), e2 = expf(s2-mx), e3 = expf(s3-mx);
            float inv = 1.f / (e0 + e1 + e2 + e3);
            sWf[s*17 + h*4 + 0] = e0*inv; sWf[s*17 + h*4 + 1] = e1*inv;
            sWf[s*17 + h*4 + 2] = e2*inv; sWf[s*17 + h*4 + 3] = e3*inv;
        }
    }
    __syncthreads();

    // ---------------- phase 1b: x3 -> A-fragment layout in sWgt --------------
    {
        int s = tid >> 1, half = tid & 1;
        int gs = gbase + s;
        int p = p_val[gs], ta = a_tok[gs], tb = b_tok[gs];
        float w[16];
        #pragma unroll
        for (int i = 0; i < 16; i++) w[i] = sWf[s*17 + i];
        const bf16x8* m3v = (const bf16x8*)(M3B + p*128);
        const bf16x8* t0  = (const bf16x8*)(O0 + p*512);
        const bf16x8* t1  = (const bf16x8*)(O1 + ta*512);
        const bf16x8* t2  = (const bf16x8*)(O2 + tb*512);
        const bf16x8* t3  = (const bf16x8*)O3g;
        int tilel = s >> 4, slr = s & 15;
        for (int jj = 0; jj < 8; jj++) {
            int c8 = half*8 + jj;               // bf16x8 group within 128 cols
            bf16x8 mv = m3v[c8];
            float v[8];
            #pragma unroll
            for (int e = 0; e < 8; e++) v[e] = (float)mv[e];
            #pragma unroll
            for (int h = 0; h < 4; h++) {
                int o8 = h*16 + c8;
                bf16x8 e0 = t0[o8], e1 = t1[o8], e2 = t2[o8], e3 = t3[o8];
                float w0 = w[h*4+0], w1 = w[h*4+1], w2 = w[h*4+2], w3 = w[h*4+3];
                #pragma unroll
                for (int e = 0; e < 8; e++)
                    v[e] += w0*(float)e0[e] + w1*(float)e1[e] + w2*(float)e2[e] + w3*(float)e3[e];
            }
            bf16x8 st;
            #pragma unroll
            for (int e = 0; e < 8; e++) st[e] = (__bf16)v[e];
            int kb = c8 >> 2, q = c8 & 3;       // frag coords
            *(bf16x8*)(sWgt + (((tilel*4 + kb)*64) + q*16 + slr)*16) = st;
        }
    }
    __syncthreads();

    // ---------------- load A-fragments (x3) into registers -------------------
    bf16x8 a[2][4];
    #pragma unroll
    for (int t = 0; t < 2; t++)
        #pragma unroll
        for (int kb = 0; kb < 4; kb++)
            a[t][kb] = *(const bf16x8*)(sWgt + (((wv*2 + t)*4 + kb)*64 + l)*16);
    __syncthreads();   // everyone done reading x3 frags; sWgt free for weights

    f32x4 acc2[2][8];
    #pragma unroll
    for (int t = 0; t < 2; t++)
        #pragma unroll
        for (int i = 0; i < 8; i++) acc2[t][i] = (f32x4){0.f, 0.f, 0.f, 0.f};

    // ---------------- MLP over 8 chunks of 64 hidden cols --------------------
    for (int cc = 0; cc < 8; cc++) {
        // stage W1 chunk (16 KB, contiguous) and W2 chunk (16 KB, 16 segments)
        #pragma unroll
        for (int ps = 0; ps < 4; ps++) {
            int off = ps*4096 + tid*16;
            *(float4*)(sWgt + off) = *(const float4*)((const char*)W1f + cc*16384 + off);
        }
        #pragma unroll
        for (int ps = 0; ps < 4; ps++) {
            int s = ps*4 + wv;                  // segment 0..15
            int kb2 = s >> 3, nb2 = s & 7;
            const float4* g = (const float4*)((const char*)W2f + ((nb2*16 + cc*2 + kb2)*64 + l)*16);
            *(float4*)(sWgt + 16384 + s*1024 + l*16) = *g;
        }
        __syncthreads();

        // MLP1: 4 col-groups of 16, B-frag regs reused across 2 tiles
        char* sHHw = sHH + wv*4608;
        #pragma unroll
        for (int nbl = 0; nbl < 4; nbl++) {
            float bv = sB[cc*64 + nbl*16 + lr];
            bf16x8 w1[4];
            #pragma unroll
            for (int kb = 0; kb < 4; kb++)
                w1[kb] = *(const bf16x8*)(sWgt + ((nbl*4 + kb)*64 + l)*16);
            #pragma unroll
            for (int t = 0; t < 2; t++) {
                f32x4 acc = (f32x4){bv, bv, bv, bv};
                #pragma unroll
                for (int kb = 0; kb < 4; kb++)
                    acc = __builtin_amdgcn_mfma_f32_16x16x32_bf16(a[t][kb], w1[kb], acc, 0, 0, 0);
                char* base = sHHw + t*2304;
                #pragma unroll
                for (int r = 0; r < 4; r++)
                    *(__bf16*)(base + (((quad*4 + r)*72) + nbl*16 + lr)*2) = (__bf16)fmaxf(acc[r], 0.f);
            }
        }

        // MLP2 partial over this chunk's 64 K
        #pragma unroll
        for (int kb2 = 0; kb2 < 2; kb2++) {
            bf16x8 h0 = *(const bf16x8*)(sHHw +          (lr*72 + kb2*32 + quad*8)*2);
            bf16x8 h1 = *(const bf16x8*)(sHHw + 2304 +   (lr*72 + kb2*32 + quad*8)*2);
            #pragma unroll
            for (int nb2 = 0; nb2 < 8; nb2++) {
                bf16x8 w2 = *(const bf16x8*)(sWgt + 16384 + ((kb2*8 + nb2)*64 + l)*16);
                acc2[0][nb2] = __builtin_amdgcn_mfma_f32_16x16x32_bf16(h0, w2, acc2[0][nb2], 0, 0, 0);
                acc2[1][nb2] = __builtin_amdgcn_mfma_f32_16x16x32_bf16(h1, w2, acc2[1][nb2], 0, 0, 0);
            }
        }
        __syncthreads();
    }

    // ---------------- residual via identity-matrix MFMA ----------------------
    #pragma unroll
    for (int k32 = 0; k32 < 4; k32++) {
        #pragma unroll
        for (int dd = 0; dd < 2; dd++) {
            int nb2 = k32*2 + dd;
            bf16x8 bi;
            #pragma unroll
            for (int j = 0; j < 8; j++)
                bi[j] = (k32*32 + quad*8 + j == nb2*16 + lr) ? (__bf16)1.0f : (__bf16)0.0f;
            acc2[0][nb2] = __builtin_amdgcn_mfma_f32_16x16x32_bf16(a[0][k32], bi, acc2[0][nb2], 0, 0, 0);
            acc2[1][nb2] = __builtin_amdgcn_mfma_f32_16x16x32_bf16(a[1][k32], bi, acc2[1][nb2], 0, 0, 0);
        }
    }

    // ---------------- stage WU (40 KB) ---------------------------------------
    #pragma unroll
    for (int ps = 0; ps < 10; ps++) {
        int off = ps*4096 + tid*16;
        *(float4*)(sWgt + off) = *(const float4*)((const char*)WUf + off);
    }
    __syncthreads();

    // ---------------- epilogue + unembed, per tile ---------------------------
    char* sHHw = sHH + wv*4608;
    #pragma unroll
    for (int t = 0; t < 2; t++) {
        // x'' = acc2 + b2 -> sHH (two 64-col panels)
        #pragma unroll
        for (int nb2 = 0; nb2 < 8; nb2++) {
            int n = nb2*16 + lr;
            float bv = sB[512 + n];
            char* base = sHHw + (nb2 >> 2)*2304;
            #pragma unroll
            for (int r = 0; r < 4; r++) {
                float v = acc2[t][nb2][r] + bv;
                *(__bf16*)(base + (((quad*4 + r)*72) + (nb2 & 3)*16 + lr)*2) = (__bf16)v;
            }
        }
        bf16x8 au[4];
        #pragma unroll
        for (int kb = 0; kb < 4; kb++)
            au[kb] = *(const bf16x8*)(sHHw + (kb >> 1)*2304 + (lr*72 + (kb & 1)*32 + quad*8)*2);
        #pragma unroll
        for (int nt = 0; nt < 10; nt++) {
            int n = nt*16 + lr;
            float bv = (n < 150) ? sB[640 + n] : 0.f;
            f32x4 acc = (f32x4){bv, bv, bv, bv};
            #pragma unroll
            for (int kb = 0; kb < 4; kb++) {
                bf16x8 wu = *(const bf16x8*)(sWgt + ((nt*4 + kb)*64 + l)*16);
                acc = __builtin_amdgcn_mfma_f32_16x16x32_bf16(au[kb], wu, acc, 0, 0, 0);
            }
            if (n < 150) {
                #pragma unroll
                for (int r = 0; r < 4; r++) {
                    int rowg = gbase + (wv*2 + t)*16 + quad*4 + r;
                    out[rowg*150 + n] = acc[r];
                }
            }
        }
    }
}

// ============================ launcher ======================================
extern "C" void kernel_launch(void* const* d_in, const int* in_sizes, int n_in,
                              void* d_out, int out_size, void* d_ws, size_t ws_size,
                              hipStream_t stream) {
    const int*   p_val = (const int*)d_in[0];
    const int*   a_tok = (const int*)d_in[1];
    const int*   b_tok = (const int*)d_in[2];
    const float* tok   = (const float*)d_in[3];
    const float* pos   = (const float*)d_in[4];
    const float* W_mem = (const float*)d_in[5];
    const float* b_mem = (const float*)d_in[6];
    const float* W_sur = (const float*)d_in[7];
    const float* b_sur = (const float*)d_in[8];
    const float* W_m2r = (const float*)d_in[9];
    const float* b_m2r = (const float*)d_in[10];
    const float* W_Q   = (const float*)d_in[11];
    const float* W_K   = (const float*)d_in[12];
    const float* W_V   = (const float*)d_in[13];
    const float* W_O   = (const float*)d_in[14];
    const float* W1    = (const float*)d_in[15];
    const float* b1    = (const float*)d_in[16];
    const float* W2    = (const float*)d_in[17];
    const float* b2    = (const float*)d_in[18];
    const float* WU    = (const float*)d_in[19];
    const float* bun   = (const float*)d_in[20];
    float* out = (float*)d_out;

    float* ws = (float*)d_ws;
    float* memvec = ws + OFF_MEMVEC;
    float* x3base = ws + OFF_X3BASE;
    float* KE     = ws + OFF_KE;
    float* KP     = ws + OFF_KP;
    float* SC     = ws + OFF_SC;
    __bf16* O0    = (__bf16*)(ws + OFF_O0);
    __bf16* O1    = (__bf16*)(ws + OFF_O1);
    __bf16* O2    = (__bf16*)(ws + OFF_O2);
    __bf16* O3    = (__bf16*)(ws + OFF_O3);
    __bf16* M3B   = (__bf16*)(ws + OFF_M3B);
    __bf16* W1f   = (__bf16*)(ws + OFF_W1F);
    __bf16* W2f   = (__bf16*)(ws + OFF_W2F);
    __bf16* WUf   = (__bf16*)(ws + OFF_WUF);

    k_P1<<<832, 256, 0, stream>>>(tok, pos, W_mem, b_mem, W_sur, b_sur, W_m2r, b_m2r,
                                  W_K, W_V, W_O, W1, W2, WU,
                                  memvec, x3base, KE, KP, O0, O1, O2, O3, W1f, W2f, WUf);
    k_P2<<<150, 256, 0, stream>>>(memvec, x3base, W_Q, W_V, W_O, KE, KP, SC, M3B);
    k_mainM<<<NBATCH/128, 256, 0, stream>>>(p_val, a_tok, b_tok, SC, O0, O1, O2, O3, M3B,
                                            W1f, W2f, WUf, b1, b2, bun, out);
}